// Round 1
// baseline (69.268 us; speedup 1.0000x reference)
//
#include <hip/hip_runtime.h>

// XGate on qutrit site INDEX=5 of L=16 qutrits, D=3, shift S=1.
// y[g] = x[ blk(g)*PER + (t + 2*RIGHT) mod PER ],  t = g mod PER
//   PER   = D * RIGHT = 3^11 = 177147
//   RIGHT = 3^10      = 59049
// Pure permutation -> memory-bound gather/copy.

#define N_TOTAL 43046721u   // 3^16
#define PER     177147u     // 3^11
#define SHIFT_T 118098u     // ((D - S) % D) * RIGHT = 2 * 59049

__global__ void XGate_71150428226262_kernel(const float* __restrict__ x,
                                            float* __restrict__ y) {
    const unsigned nchunks = (N_TOTAL + 3u) / 4u;  // 10,761,681 float4 chunks
    const unsigned stride = gridDim.x * blockDim.x;
    for (unsigned v = blockIdx.x * blockDim.x + threadIdx.x; v < nchunks; v += stride) {
        const unsigned g = v * 4u;
        float out[4];
#pragma unroll
        for (int e = 0; e < 4; ++e) {
            unsigned gi = g + (unsigned)e;
            if (gi < N_TOTAL) {
                unsigned a  = gi / PER;            // magic-mul, cheap
                unsigned t  = gi - a * PER;
                unsigned ts = t + SHIFT_T;
                if (ts >= PER) ts -= PER;          // single conditional subtract suffices
                out[e] = x[a * PER + ts];
            } else {
                out[e] = 0.0f;
            }
        }
        if (g + 3u < N_TOTAL) {
            *reinterpret_cast<float4*>(y + g) = make_float4(out[0], out[1], out[2], out[3]);
        } else {
            // tail: N_TOTAL % 4 == 1, one scalar element
            for (unsigned e = 0; e < 4u && g + e < N_TOTAL; ++e) y[g + e] = out[e];
        }
    }
}

extern "C" void kernel_launch(void* const* d_in, const int* in_sizes, int n_in,
                              void* d_out, int out_size, void* d_ws, size_t ws_size,
                              hipStream_t stream) {
    const float* x = (const float*)d_in[0];   // state vector, 3^16 floats
    // d_in[1] is M (3x3 shift matrix) — permutation is hardcoded (D=3, S=1)
    float* y = (float*)d_out;

    const int block = 256;
    const int grid  = 2048;  // 256 CUs x 8 blocks/CU; grid-stride covers the rest
    XGate_71150428226262_kernel<<<grid, block, 0, stream>>>(x, y);
}